// Round 1
// baseline (316.534 us; speedup 1.0000x reference)
//
#include <hip/hip_runtime.h>
#include <hip/hip_bf16.h>

// B=4096, L=32, V=256. P=0.1.
// Outputs (flat concat, all f32):
//   [0]           out      : B*L*V  = 33554432
//   [33554432]    sym_sum  : B      = 4096
//   [33558528]    sym      : B*L    = 131072
//   [33689600]    ent_sum  : B      = 4096
//   [33693696]    ent      : B*L    = 131072

// out[b,l,k] = (noise[b,l,(k+1)&255] < P) ? 0 : messages[b,l,k],
// except k==254 is never masked (noise index 255 doesn't exist).
__global__ void __launch_bounds__(256) chan_mask_kernel(
    const float4* __restrict__ msg4,   // B*L*64 float4
    const float*  __restrict__ noise,  // B*L*255 floats
    float4* __restrict__ out4,
    int nvec)                          // B*L*64
{
    const int stride = gridDim.x * blockDim.x;
    for (int v = blockIdx.x * blockDim.x + threadIdx.x; v < nvec; v += stride) {
        const int row = v >> 6;            // which (b,l) row
        const int k0  = (v & 63) << 2;     // first output column of this vec4
        const float* nrow = noise + row * 255;
        float4 m = msg4[v];
        float n0, n1, n2, n3;
        if (k0 != 252) {
            // outputs k0..k0+3 -> noise k0+1..k0+4 (all in [1,252+?]: max 252)
            n0 = nrow[k0 + 1];
            n1 = nrow[k0 + 2];
            n2 = nrow[k0 + 3];
            n3 = nrow[k0 + 4];
        } else {
            // outputs 252,253,254,255 -> noise 253, 254, (none), 0
            n0 = nrow[253];
            n1 = nrow[254];
            n2 = 1.0f;       // column 254 never masked
            n3 = nrow[0];
        }
        m.x = (n0 < 0.1f) ? 0.0f : m.x;
        m.y = (n1 < 0.1f) ? 0.0f : m.y;
        m.z = (n2 < 0.1f) ? 0.0f : m.z;
        m.w = (n3 < 0.1f) ? 0.0f : m.w;
        out4[v] = m;
    }
}

__global__ void __launch_bounds__(256) ent_kernel(
    const float* __restrict__ entropy,  // [B*L]
    float* __restrict__ o_sym_sum,      // [B]
    float* __restrict__ o_sym,          // [B*L]
    float* __restrict__ o_ent_sum,      // [B]
    float* __restrict__ o_ent,          // [B*L]
    int n)                              // B*L
{
    // C = -(p*log2(p) + q*log2(q)) + log2(V-2), p=0.1, V=256
    const float C = (float)8.457680280361447;
    int i = blockIdx.x * blockDim.x + threadIdx.x;
    if (i >= n) return;
    float e = entropy[i];
    o_sym[i] = e + C;
    o_ent[i] = e;
    // row-sum over L=32 contiguous elements; lanes [32k,32k+31] hold one row
    float es = e;
    #pragma unroll
    for (int m = 1; m < 32; m <<= 1) es += __shfl_xor(es, m);
    if ((threadIdx.x & 31) == 0) {
        int row = i >> 5;
        o_ent_sum[row] = es;
        o_sym_sum[row] = es + 32.0f * C;
    }
}

extern "C" void kernel_launch(void* const* d_in, const int* in_sizes, int n_in,
                              void* d_out, int out_size, void* d_ws, size_t ws_size,
                              hipStream_t stream) {
    const float* messages = (const float*)d_in[0];  // [4096,32,256]
    const float* entropy  = (const float*)d_in[1];  // [4096,32]
    const float* noise    = (const float*)d_in[2];  // [4096,32,255]

    float* out = (float*)d_out;
    const int BLV  = 4096 * 32 * 256;   // 33554432
    const int BL   = 4096 * 32;         // 131072
    const int B    = 4096;

    float* o_out     = out;
    float* o_sym_sum = out + BLV;
    float* o_sym     = o_sym_sum + B;
    float* o_ent_sum = o_sym + BL;
    float* o_ent     = o_ent_sum + B;

    const int nvec = BLV / 4;           // 8388608 float4s
    const int blk = 256;
    const int grid1 = 2048;             // grid-stride, ~8 blocks/CU
    chan_mask_kernel<<<grid1, blk, 0, stream>>>(
        (const float4*)messages, noise, (float4*)o_out, nvec);

    const int grid2 = (BL + blk - 1) / blk;  // 512
    ent_kernel<<<grid2, blk, 0, stream>>>(
        entropy, o_sym_sum, o_sym, o_ent_sum, o_ent, BL);
}

// Round 3
// 314.696 us; speedup vs baseline: 1.0058x; 1.0058x over previous
//
#include <hip/hip_runtime.h>
#include <hip/hip_bf16.h>

// B=4096, L=32, V=256. P=0.1.
// Outputs (flat concat, all f32):
//   [0]           out      : B*L*V  = 33554432
//   [33554432]    sym_sum  : B      = 4096
//   [33558528]    sym      : B*L    = 131072
//   [33689600]    ent_sum  : B      = 4096
//   [33693696]    ent      : B*L    = 131072

#define RPB 16  // rows (b,l) per block; 16*255=4080 floats of noise = 1020 float4 (16B-aligned chunk)

// out[b,l,k] = (noise[b,l,k+1] < P) ? 0 : messages[b,l,k] for k<=253,
// k==254 never masked, k==255 masked iff noise[b,l,0] < P.
__global__ void __launch_bounds__(256) chan_mask_kernel(
    const float4* __restrict__ msg4,    // BL*64 float4
    const float4* __restrict__ noise4,  // BL*255/4 float4, flat
    float4* __restrict__ out4)
{
    __shared__ float nz[RPB * 255];     // 4080 floats = 16320 B
    const int t = threadIdx.x;
    const int blk = blockIdx.x;         // handles rows [blk*16, blk*16+16)
    const int base = blk * (RPB * 64);  // first float4 of this block's msg/out

    // Issue the 4 message loads early (independent of LDS) for MLP.
    float4 m0 = msg4[base + t];
    float4 m1 = msg4[base + t + 256];
    float4 m2 = msg4[base + t + 512];
    float4 m3 = msg4[base + t + 768];

    // Stage 1020 float4s of noise, fully coalesced (16B/lane, unit stride).
    const float4* nsrc = noise4 + blk * (RPB * 255 / 4);  // 1020 per block
    #pragma unroll
    for (int j = 0; j < 4; ++j) {
        int idx = t + 256 * j;
        if (idx < RPB * 255 / 4)
            *reinterpret_cast<float4*>(&nz[4 * idx]) = nsrc[idx];
    }
    __syncthreads();

    float4 mm[4] = {m0, m1, m2, m3};
    #pragma unroll
    for (int j = 0; j < 4; ++j) {
        int f = t + 256 * j;            // local float4 index, 0..1023
        int row = f >> 6;               // local row 0..15
        int k0 = (f & 63) << 2;         // first output column, 0..252
        const float* nrow = &nz[row * 255];
        float n0, n1, n2, n3;
        if (k0 != 252) {
            n0 = nrow[k0 + 1];
            n1 = nrow[k0 + 2];
            n2 = nrow[k0 + 3];
            n3 = nrow[k0 + 4];
        } else {
            // outputs 252,253,254,255 <- noise 253, 254, (none), 0
            n0 = nrow[253];
            n1 = nrow[254];
            n2 = 1.0f;                  // column 254 never masked
            n3 = nrow[0];
        }
        float4 m = mm[j];
        m.x = (n0 < 0.1f) ? 0.0f : m.x;
        m.y = (n1 < 0.1f) ? 0.0f : m.y;
        m.z = (n2 < 0.1f) ? 0.0f : m.z;
        m.w = (n3 < 0.1f) ? 0.0f : m.w;
        out4[base + f] = m;
    }
}

__global__ void __launch_bounds__(256) ent_kernel(
    const float* __restrict__ entropy,  // [B*L]
    float* __restrict__ o_sym_sum,      // [B]
    float* __restrict__ o_sym,          // [B*L]
    float* __restrict__ o_ent_sum,      // [B]
    float* __restrict__ o_ent,          // [B*L]
    int n)                              // B*L
{
    // C = -(p*log2(p) + q*log2(q)) + log2(V-2), p=0.1, V=256
    const float C = (float)8.457680280361447;
    int i = blockIdx.x * blockDim.x + threadIdx.x;
    if (i >= n) return;
    float e = entropy[i];
    o_sym[i] = e + C;
    o_ent[i] = e;
    // row-sum over L=32 contiguous elements; lanes [32k,32k+31] hold one row
    float es = e;
    #pragma unroll
    for (int m = 1; m < 32; m <<= 1) es += __shfl_xor(es, m);
    if ((threadIdx.x & 31) == 0) {
        int row = i >> 5;
        o_ent_sum[row] = es;
        o_sym_sum[row] = es + 32.0f * C;
    }
}

extern "C" void kernel_launch(void* const* d_in, const int* in_sizes, int n_in,
                              void* d_out, int out_size, void* d_ws, size_t ws_size,
                              hipStream_t stream) {
    const float* messages = (const float*)d_in[0];  // [4096,32,256]
    const float* entropy  = (const float*)d_in[1];  // [4096,32]
    const float* noise    = (const float*)d_in[2];  // [4096,32,255]

    float* out = (float*)d_out;
    const int BLV = 4096 * 32 * 256;   // 33554432
    const int BL  = 4096 * 32;         // 131072
    const int B   = 4096;

    float* o_out     = out;
    float* o_sym_sum = out + BLV;
    float* o_sym     = o_sym_sum + B;
    float* o_ent_sum = o_sym + BL;
    float* o_ent     = o_ent_sum + B;

    const int blk = 256;
    const int grid1 = BL / RPB;        // 8192 blocks, 16 rows each
    chan_mask_kernel<<<grid1, blk, 0, stream>>>(
        (const float4*)messages, (const float4*)noise, (float4*)o_out);

    const int grid2 = (BL + blk - 1) / blk;  // 512
    ent_kernel<<<grid2, blk, 0, stream>>>(
        entropy, o_sym_sum, o_sym, o_ent_sum, o_ent, BL);
}